// Round 13
// baseline (341.075 us; speedup 1.0000x reference)
//
#include <hip/hip_runtime.h>
#include <math.h>

#define NNODES 50000
#define NEDGES 800000
#define FDIM 128
#define NBUCKET 196     // buckets of 256 nodes: 196*256 = 50176 >= 50000
#define BCAP 6144       // capacity per bucket (mean 4082, +32 sigma)
#define ABLK 261        // pass-A workgroups
#define EPWA 3072       // edges per pass-A wg (261*3072 >= 800000)
#define MGRID 782       // ceil(50000/64) 64-row tiles

typedef unsigned short ushortT;
typedef unsigned int uintT;
typedef __attribute__((ext_vector_type(8))) short short8;
typedef __attribute__((ext_vector_type(4))) float floatx4;

__device__ __forceinline__ float gelu_erf(float x){
    return 0.5f * x * (1.0f + erff(x * 0.70710678118654752f));
}
// bf16 helpers
__device__ __forceinline__ float bflo(uintT u){ return __uint_as_float(u << 16); }
__device__ __forceinline__ float bfhi(uintT u){ return __uint_as_float(u & 0xFFFF0000u); }
__device__ __forceinline__ ushortT f2bf(float f){
    uintT u = __float_as_uint(f);
    return (ushortT)((u + 0x7FFFu + ((u >> 16) & 1u)) >> 16);   // RNE
}
// truncation split: f = hi + lo_resid; both bf16 (trunc). Residual error ~2^-16 rel.
__device__ __forceinline__ void split_bf16(float f, ushortT& hi, ushortT& lo){
    uintT u = __float_as_uint(f);
    hi = (ushortT)(u >> 16);
    float fhi = __uint_as_float(u & 0xFFFF0000u);
    lo = (ushortT)(__float_as_uint(f - fhi) >> 16);
}

// ---------------- weight prepack + gcur zero ----------------
// blocks 0-3: 128x128 weights -> bf16 hi/lo planes in B-frag order.
//   off = ((kc*8+nt)*64 + lane)*8 + j   (kc=k>>5, quad=(k>>3)&3, j=k&7)
// block 4: lw2 (128x16) compact: off = (kc*64+lane)*8 + j; also zeros gcur.
__global__ __launch_bounds__(256) void k_packW(const float* __restrict__ Wa,
                                               const float* __restrict__ Wb,
                                               const float* __restrict__ Wc,
                                               const float* __restrict__ Wd,
                                               const float* __restrict__ We,
                                               ushortT* __restrict__ Wp,
                                               int* __restrict__ gcur){
    int l = blockIdx.x;
    int t = threadIdx.x;
    if (l < 4){
        const float* W = (l==0) ? Wa : (l==1) ? Wb : (l==2) ? Wc : Wd;
        ushortT* hiP = Wp + (size_t)l*2*16384;
        ushortT* loP = hiP + 16384;
        for (int idx = t; idx < 16384; idx += 256){
            int k = idx >> 7, n = idx & 127;
            ushortT hi, lo;
            split_bf16(W[idx], hi, lo);
            int kc = k >> 5, quad = (k >> 3) & 3, j = k & 7;
            int nt = n >> 4, lane = (n & 15) + (quad << 4);
            int off = ((kc*8 + nt)*64 + lane)*8 + j;
            hiP[off] = hi;
            loP[off] = lo;
        }
    } else {
        if (t < NBUCKET) gcur[t] = 0;
        ushortT* hiP = Wp + (size_t)4*2*16384;
        ushortT* loP = hiP + 2048;
        for (int idx = t; idx < 2048; idx += 256){
            int k = idx >> 4, n = idx & 15;
            ushortT hi, lo;
            split_bf16(We[idx], hi, lo);
            int kc = k >> 5, quad = (k >> 3) & 3, j = k & 7;
            int lane = n + (quad << 4);
            int off = (kc*64 + lane)*8 + j;
            hiP[off] = hi;
            loP[off] = lo;
        }
    }
}

// ---------------- CSR build ----------------
__global__ __launch_bounds__(256) void k_bucketA(const int* __restrict__ ei,
                                                 int* __restrict__ gcur,
                                                 uintT* __restrict__ bucket){
    __shared__ int hist[NBUCKET];
    __shared__ int base[NBUCKET];
    int t = threadIdx.x;
    if (t < NBUCKET) hist[t] = 0;
    __syncthreads();
    int e0 = blockIdx.x * EPWA;
    int cr_c[12], cr_r[12];
    #pragma unroll
    for (int p = 0; p < 12; p++){
        int e = e0 + p*256 + t;
        if (e < NEDGES){
            cr_r[p] = ei[e];
            cr_c[p] = ei[NEDGES + e];
            atomicAdd(&hist[cr_c[p] >> 8], 1);
        } else cr_c[p] = -1;
    }
    __syncthreads();
    if (t < NBUCKET){
        base[t] = atomicAdd(&gcur[t], hist[t]);
        hist[t] = 0;   // reuse as local cursor
    }
    __syncthreads();
    #pragma unroll
    for (int p = 0; p < 12; p++){
        int c = cr_c[p];
        if (c >= 0){
            int b = c >> 8;
            int lp = atomicAdd(&hist[b], 1);
            bucket[(size_t)b*BCAP + base[b] + lp] = ((uintT)c << 16) | (uintT)cr_r[p];
        }
    }
}

__global__ __launch_bounds__(256) void k_bucketB(const int* __restrict__ gcur,
                                                 const uintT* __restrict__ bucket,
                                                 int* __restrict__ offs,
                                                 float* __restrict__ dinv,
                                                 ushortT* __restrict__ csr2){
    __shared__ int sm[256];
    __shared__ int hist[256];
    __shared__ int lcur[256];
    int b = blockIdx.x;
    int t = threadIdx.x;
    int n0 = b << 8;

    int gv = (t < NBUCKET) ? gcur[t] : 0;
    sm[t] = gv;
    __syncthreads();
    for (int off = 1; off < 256; off <<= 1){
        int tv = (t >= off) ? sm[t-off] : 0;
        __syncthreads();
        sm[t] += tv;
        __syncthreads();
    }
    __shared__ int bbase_s;
    if (t == b) bbase_s = sm[t] - gv;
    hist[t] = 0;
    __syncthreads();
    int bbase = bbase_s;
    int count = gcur[b];
    const uintT* src = bucket + (size_t)b*BCAP;

    for (int i = t; i < count; i += 256)
        atomicAdd(&hist[(src[i] >> 16) & 255], 1);
    __syncthreads();

    int v = hist[t];
    sm[t] = v;
    __syncthreads();
    for (int off = 1; off < 256; off <<= 1){
        int tv = (t >= off) ? sm[t-off] : 0;
        __syncthreads();
        sm[t] += tv;
        __syncthreads();
    }
    int excl = bbase + sm[t] - v;
    int node = n0 + t;
    if (node <= NNODES) offs[node] = excl;
    if (node < NNODES) dinv[node] = rsqrtf((float)(v + 1));
    if (b == NBUCKET-1 && t == 255) offs[NNODES] = NEDGES;
    lcur[t] = excl;
    __syncthreads();

    for (int i = t; i < count; i += 256){
        uintT e = src[i];
        int pos = atomicAdd(&lcur[(e >> 16) & 255], 1);
        csr2[pos] = (ushortT)(e & 0xFFFFu);
    }
}

// ---------------- aggregate phase: 64 nodes -> LDS H tile (uint bf16-pairs, pitch 66) --
// Y row-major: node stride 64 uints (128 bf16). Wave per node (gather = 256B coalesced).
__device__ __forceinline__ void agg_phase(const uintT* __restrict__ Y2,
                                          const float* __restrict__ dinv,
                                          const int* __restrict__ offs,
                                          const ushortT* __restrict__ csr2,
                                          const float* __restrict__ bias,
                                          uintT* __restrict__ Hs, int row0,
                                          int wave, int lane){
    float2 bv = ((const float2*)bias)[lane];
    for (int g = 0; g < 16; g++){
        int lrow = (g << 2) + wave;
        int node = row0 + lrow;
        float2 acc = make_float2(0.f, 0.f);
        float dc = 0.f;
        if (node < NNODES){
            dc = dinv[node];
            uintT a0 = Y2[(size_t)node*64 + lane];
            acc.x = bflo(a0); acc.y = bfhi(a0);
            int e0 = offs[node], e1 = offs[node+1];
            int e = e0;
            for (; e + 7 < e1; e += 8){
                int s0 = csr2[e+0];
                int s1 = csr2[e+1];
                int s2 = csr2[e+2];
                int s3 = csr2[e+3];
                int s4 = csr2[e+4];
                int s5 = csr2[e+5];
                int s6 = csr2[e+6];
                int s7 = csr2[e+7];
                uintT q0 = Y2[(size_t)s0*64 + lane];
                uintT q1 = Y2[(size_t)s1*64 + lane];
                uintT q2 = Y2[(size_t)s2*64 + lane];
                uintT q3 = Y2[(size_t)s3*64 + lane];
                uintT q4 = Y2[(size_t)s4*64 + lane];
                uintT q5 = Y2[(size_t)s5*64 + lane];
                uintT q6 = Y2[(size_t)s6*64 + lane];
                uintT q7 = Y2[(size_t)s7*64 + lane];
                acc.x += bflo(q0); acc.y += bfhi(q0);
                acc.x += bflo(q1); acc.y += bfhi(q1);
                acc.x += bflo(q2); acc.y += bfhi(q2);
                acc.x += bflo(q3); acc.y += bfhi(q3);
                acc.x += bflo(q4); acc.y += bfhi(q4);
                acc.x += bflo(q5); acc.y += bfhi(q5);
                acc.x += bflo(q6); acc.y += bfhi(q6);
                acc.x += bflo(q7); acc.y += bfhi(q7);
            }
            for (; e + 1 < e1; e += 2){
                int s0 = csr2[e], s1 = csr2[e+1];
                uintT q0 = Y2[(size_t)s0*64 + lane];
                uintT q1 = Y2[(size_t)s1*64 + lane];
                acc.x += bflo(q0); acc.y += bfhi(q0);
                acc.x += bflo(q1); acc.y += bfhi(q1);
            }
            if (e < e1){
                uintT q = Y2[(size_t)csr2[e]*64 + lane];
                acc.x += bflo(q); acc.y += bfhi(q);
            }
        }
        float ox = gelu_erf(fmaf(dc, acc.x, bv.x));
        float oy = gelu_erf(fmaf(dc, acc.y, bv.y));
        Hs[lrow*66 + lane] = (uintT)f2bf(ox) | ((uintT)f2bf(oy) << 16);
    }
}

// ---------------- MFMA GEMM (fp32 A, layer 1): [N,128]x[128,128] split-bf16 x3 -------
// Out: Ys row-major bf16, scaled by dinv[row].
__global__ __launch_bounds__(256) void k_mfma_f32(const float* __restrict__ A,
                                                  const ushortT* __restrict__ Wp,
                                                  const float* __restrict__ scale,
                                                  const float* __restrict__ dinv,
                                                  ushortT* __restrict__ Yb){
    __shared__ float As[64*132];
    int t = threadIdx.x;
    int wave = t >> 6, lane = t & 63;
    int r = lane & 15, quad = lane >> 4;
    int row0 = blockIdx.x*64;
    int m0 = row0 + wave*16;
    const ushortT* WpLo = Wp + 16384;

    #pragma unroll
    for (int p = 0; p < 8; p++){
        int idx = p*256 + t;
        int rr = idx >> 5;
        int c4 = idx & 31;
        int gr = row0 + rr;
        float4 v = make_float4(0.f,0.f,0.f,0.f);
        if (gr < NNODES) v = *(const float4*)&A[(size_t)gr*FDIM + c4*4];
        float4 s = *(const float4*)&scale[c4*4];
        v.x*=s.x; v.y*=s.y; v.z*=s.z; v.w*=s.w;
        *(float4*)&As[rr*132 + c4*4] = v;
    }
    __syncthreads();

    floatx4 acc[8];
    #pragma unroll
    for (int nt = 0; nt < 8; nt++) acc[nt] = (floatx4){0.f,0.f,0.f,0.f};

    int arl = wave*16 + r;
    #pragma unroll
    for (int kc = 0; kc < 4; kc++){
        int kb = kc*32 + quad*8;
        float4 a0 = *(const float4*)&As[arl*132 + kb];
        float4 a1 = *(const float4*)&As[arl*132 + kb + 4];
        float av[8] = {a0.x, a0.y, a0.z, a0.w, a1.x, a1.y, a1.z, a1.w};
        short8 ahi, alo;
        #pragma unroll
        for (int e = 0; e < 8; e++){
            ushortT h, l;
            split_bf16(av[e], h, l);
            ahi[e] = (short)h;
            alo[e] = (short)l;
        }
        #pragma unroll
        for (int nt = 0; nt < 8; nt++){
            size_t boff = (size_t)(((kc*8 + nt)*64 + lane))*8;
            short8 bhi = *(const short8*)&Wp[boff];
            short8 blo = *(const short8*)&WpLo[boff];
            acc[nt] = __builtin_amdgcn_mfma_f32_16x16x32_bf16(ahi, bhi, acc[nt], 0, 0, 0);
            acc[nt] = __builtin_amdgcn_mfma_f32_16x16x32_bf16(alo, bhi, acc[nt], 0, 0, 0);
            acc[nt] = __builtin_amdgcn_mfma_f32_16x16x32_bf16(ahi, blo, acc[nt], 0, 0, 0);
        }
    }

    int orow0 = m0 + quad*4;
    float4 dv = *(const float4*)&dinv[orow0];
    float dva[4] = {dv.x, dv.y, dv.z, dv.w};
    #pragma unroll
    for (int nt = 0; nt < 8; nt++){
        int n = nt*16 + r;
        #pragma unroll
        for (int reg = 0; reg < 4; reg++){
            int orow = orow0 + reg;
            if (orow < NNODES)
                Yb[(size_t)orow*FDIM + n] = f2bf(acc[nt][reg] * dva[reg]);
        }
    }
}

// ---------------- fused aggregate + GEMM (layers 2,3) -------------------------------
// Phase 1: gather-aggregate 64 nodes into LDS H. Phase 2: H @ W (split-W x2 MFMA),
// out Ys row-major bf16 * dinv.
__global__ __launch_bounds__(256) void k_agg_gemm(const uintT* __restrict__ Yin,
                                                  const float* __restrict__ dinv,
                                                  const int* __restrict__ offs,
                                                  const ushortT* __restrict__ csr2,
                                                  const float* __restrict__ bias,
                                                  const ushortT* __restrict__ Wp,
                                                  ushortT* __restrict__ Yout){
    __shared__ uintT Hs[64*66];
    int t = threadIdx.x;
    int wave = t >> 6, lane = t & 63;
    int row0 = blockIdx.x*64;
    agg_phase(Yin, dinv, offs, csr2, bias, Hs, row0, wave, lane);
    __syncthreads();

    int r = lane & 15, quad = lane >> 4;
    const ushortT* HsS = (const ushortT*)Hs;
    const ushortT* WpLo = Wp + 16384;
    int arl = wave*16 + r;
    short8 afr[4];
    #pragma unroll
    for (int kc = 0; kc < 4; kc++)
        afr[kc] = *(const short8*)&HsS[arl*132 + kc*32 + quad*8];

    floatx4 acc[8];
    #pragma unroll
    for (int nt = 0; nt < 8; nt++) acc[nt] = (floatx4){0.f,0.f,0.f,0.f};
    #pragma unroll
    for (int kc = 0; kc < 4; kc++){
        #pragma unroll
        for (int nt = 0; nt < 8; nt++){
            size_t boff = (size_t)(((kc*8 + nt)*64 + lane))*8;
            short8 bhi = *(const short8*)&Wp[boff];
            short8 blo = *(const short8*)&WpLo[boff];
            acc[nt] = __builtin_amdgcn_mfma_f32_16x16x32_bf16(afr[kc], bhi, acc[nt], 0, 0, 0);
            acc[nt] = __builtin_amdgcn_mfma_f32_16x16x32_bf16(afr[kc], blo, acc[nt], 0, 0, 0);
        }
    }

    int m0 = row0 + wave*16;
    int orow0 = m0 + quad*4;
    float4 dv = *(const float4*)&dinv[orow0];
    float dva[4] = {dv.x, dv.y, dv.z, dv.w};
    #pragma unroll
    for (int nt = 0; nt < 8; nt++){
        int n = nt*16 + r;
        #pragma unroll
        for (int reg = 0; reg < 4; reg++){
            int orow = orow0 + reg;
            if (orow < NNODES)
                Yout[(size_t)orow*FDIM + n] = f2bf(acc[nt][reg] * dva[reg]);
        }
    }
}

// ---------------- fused final: aggregate + gelu(H@lw1+lb1)@lw2 + lb2 -----------------
__global__ __launch_bounds__(256) void k_agg_final(const uintT* __restrict__ Yin,
                                                   const float* __restrict__ dinv,
                                                   const int* __restrict__ offs,
                                                   const ushortT* __restrict__ csr2,
                                                   const float* __restrict__ bias,
                                                   const ushortT* __restrict__ Wp1,
                                                   const ushortT* __restrict__ Wp2,
                                                   const float* __restrict__ lb1,
                                                   const float* __restrict__ lb2,
                                                   float* __restrict__ out){
    __shared__ uintT Hs[64*66];
    __shared__ ushortT Ps[64*136];
    int t = threadIdx.x;
    int wave = t >> 6, lane = t & 63;
    int row0 = blockIdx.x*64;
    agg_phase(Yin, dinv, offs, csr2, bias, Hs, row0, wave, lane);
    __syncthreads();

    int r = lane & 15, quad = lane >> 4;
    const ushortT* HsS = (const ushortT*)Hs;
    const ushortT* Wp1Lo = Wp1 + 16384;
    const ushortT* Wp2Lo = Wp2 + 2048;
    int arl = wave*16 + r;
    short8 afr[4];
    #pragma unroll
    for (int kc = 0; kc < 4; kc++)
        afr[kc] = *(const short8*)&HsS[arl*132 + kc*32 + quad*8];

    floatx4 acc[8];
    #pragma unroll
    for (int nt = 0; nt < 8; nt++) acc[nt] = (floatx4){0.f,0.f,0.f,0.f};
    #pragma unroll
    for (int kc = 0; kc < 4; kc++){
        #pragma unroll
        for (int nt = 0; nt < 8; nt++){
            size_t boff = (size_t)(((kc*8 + nt)*64 + lane))*8;
            short8 bhi = *(const short8*)&Wp1[boff];
            short8 blo = *(const short8*)&Wp1Lo[boff];
            acc[nt] = __builtin_amdgcn_mfma_f32_16x16x32_bf16(afr[kc], bhi, acc[nt], 0, 0, 0);
            acc[nt] = __builtin_amdgcn_mfma_f32_16x16x32_bf16(afr[kc], blo, acc[nt], 0, 0, 0);
        }
    }

    // P -> gelu -> bf16 LDS
    int lrow0 = wave*16 + quad*4;
    #pragma unroll
    for (int nt = 0; nt < 8; nt++){
        int n = nt*16 + r;
        float bv = lb1[n];
        #pragma unroll
        for (int reg = 0; reg < 4; reg++)
            Ps[(lrow0 + reg)*136 + n] = f2bf(gelu_erf(acc[nt][reg] + bv));
    }
    __syncthreads();

    floatx4 acc2 = (floatx4){0.f,0.f,0.f,0.f};
    #pragma unroll
    for (int kc = 0; kc < 4; kc++){
        short8 a2 = *(const short8*)&Ps[(wave*16 + r)*136 + kc*32 + quad*8];
        short8 bhi = *(const short8*)&Wp2[(size_t)(kc*64 + lane)*8];
        short8 blo = *(const short8*)&Wp2Lo[(size_t)(kc*64 + lane)*8];
        acc2 = __builtin_amdgcn_mfma_f32_16x16x32_bf16(a2, bhi, acc2, 0, 0, 0);
        acc2 = __builtin_amdgcn_mfma_f32_16x16x32_bf16(a2, blo, acc2, 0, 0, 0);
    }
    float bv2 = lb2[r];
    int m0 = row0 + wave*16;
    #pragma unroll
    for (int reg = 0; reg < 4; reg++){
        int orow = m0 + quad*4 + reg;
        if (orow < NNODES)
            out[(size_t)orow*16 + r] = acc2[reg] + bv2;
    }
}

extern "C" void kernel_launch(void* const* d_in, const int* in_sizes, int n_in,
                              void* d_out, int out_size, void* d_ws, size_t ws_size,
                              hipStream_t stream) {
    const float* x    = (const float*)d_in[0];
    const int*   ei   = (const int*)d_in[1];
    const float* imp  = (const float*)d_in[2];
    const float* W1   = (const float*)d_in[3];
    const float* b1   = (const float*)d_in[4];
    const float* W2   = (const float*)d_in[5];
    const float* b2   = (const float*)d_in[6];
    const float* W3   = (const float*)d_in[7];
    const float* b3   = (const float*)d_in[8];
    const float* lw1  = (const float*)d_in[9];
    const float* lb1  = (const float*)d_in[10];
    const float* lw2  = (const float*)d_in[11];
    const float* lb2  = (const float*)d_in[12];
    float* out = (float*)d_out;

    // workspace layout (units of 4 bytes)
    int*   offs   = (int*)d_ws;                          // 50001 (pad to 50048)
    int*   gcur   = (int*)d_ws + 50048;                  // 196 (pad to 50304)
    float* dinv   = (float*)d_ws + 50304;                // 50000 (pad to 100480)
    ushortT* csr2 = (ushortT*)((int*)d_ws + 100480);     // 800000 ushort (1.6 MB)
    uintT* bucket = (uintT*)((int*)d_ws + 500480);       // 196*6144 uint (4.8 MB)
    ushortT* Wp   = (ushortT*)((int*)d_ws + 1704704);    // 4*32768 + 4096 ushort (~270 KB)
    uintT* bufY0  = (uintT*)((int*)d_ws + 1772288);      // 50048*64 uints (12.8 MB) row-major bf16
    uintT* bufY1  = (uintT*)((int*)d_ws + 4976288);      // 50048*64 uints (12.8 MB)

    dim3 B(256);
    // ---- weight prepack (+gcur zero) + CSR build ----
    k_packW  <<<5, B, 0, stream>>>(W1, W2, W3, lw1, lw2, Wp, gcur);
    k_bucketA<<<ABLK, B, 0, stream>>>(ei, gcur, bucket);
    k_bucketB<<<NBUCKET, B, 0, stream>>>(gcur, bucket, offs, dinv, csr2);

    // ---- layer 1 GEMM (fp32 x * importance) -> Ys0 ----
    k_mfma_f32<<<MGRID, B, 0, stream>>>(x, Wp + 0*32768, imp, dinv, (ushortT*)bufY0);
    // ---- fused aggregate+GEMM layers 2,3 ----
    k_agg_gemm<<<MGRID, B, 0, stream>>>(bufY0, dinv, offs, csr2, b1, Wp + 1*32768, (ushortT*)bufY1);
    k_agg_gemm<<<MGRID, B, 0, stream>>>(bufY1, dinv, offs, csr2, b2, Wp + 2*32768, (ushortT*)bufY0);
    // ---- fused aggregate + MLP head ----
    k_agg_final<<<MGRID, B, 0, stream>>>(bufY0, dinv, offs, csr2, b3,
                                         Wp + 3*32768, Wp + 4*32768, lb1, lb2, out);
}

// Round 14
// 300.902 us; speedup vs baseline: 1.1335x; 1.1335x over previous
//
#include <hip/hip_runtime.h>
#include <math.h>

#define NNODES 50000
#define NEDGES 800000
#define FDIM 128
#define NBUCKET 196     // buckets of 256 nodes: 196*256 = 50176 >= 50000
#define BCAP 6144       // capacity per bucket (mean 4082, +32 sigma)
#define ABLK 261        // pass-A workgroups
#define EPWA 3072       // edges per pass-A wg (261*3072 >= 800000)
#define MGRID 782       // ceil(50000/64) MFMA-GEMM blocks

typedef unsigned short ushortT;
typedef unsigned int uintT;
typedef __attribute__((ext_vector_type(8))) short short8;
typedef __attribute__((ext_vector_type(4))) float floatx4;

__device__ __forceinline__ float gelu_erf(float x){
    return 0.5f * x * (1.0f + erff(x * 0.70710678118654752f));
}
// bf16 helpers
__device__ __forceinline__ float bflo(uintT u){ return __uint_as_float(u << 16); }
__device__ __forceinline__ float bfhi(uintT u){ return __uint_as_float(u & 0xFFFF0000u); }
__device__ __forceinline__ ushortT f2bf(float f){
    uintT u = __float_as_uint(f);
    return (ushortT)((u + 0x7FFFu + ((u >> 16) & 1u)) >> 16);   // RNE
}
// truncation split: f = hi + lo_resid; both bf16 (trunc). Residual error ~2^-16 rel.
__device__ __forceinline__ void split_bf16(float f, ushortT& hi, ushortT& lo){
    uintT u = __float_as_uint(f);
    hi = (ushortT)(u >> 16);
    float fhi = __uint_as_float(u & 0xFFFF0000u);
    lo = (ushortT)(__float_as_uint(f - fhi) >> 16);
}

// ---------------- weight prepack + gcur zero ----------------
__global__ __launch_bounds__(256) void k_packW(const float* __restrict__ Wa,
                                               const float* __restrict__ Wb,
                                               const float* __restrict__ Wc,
                                               const float* __restrict__ Wd,
                                               const float* __restrict__ We,
                                               ushortT* __restrict__ Wp,
                                               int* __restrict__ gcur){
    int l = blockIdx.x;
    int t = threadIdx.x;
    if (l < 4){
        const float* W = (l==0) ? Wa : (l==1) ? Wb : (l==2) ? Wc : Wd;
        ushortT* hiP = Wp + (size_t)l*2*16384;
        ushortT* loP = hiP + 16384;
        for (int idx = t; idx < 16384; idx += 256){
            int k = idx >> 7, n = idx & 127;
            ushortT hi, lo;
            split_bf16(W[idx], hi, lo);
            int kc = k >> 5, quad = (k >> 3) & 3, j = k & 7;
            int nt = n >> 4, lane = (n & 15) + (quad << 4);
            int off = ((kc*8 + nt)*64 + lane)*8 + j;
            hiP[off] = hi;
            loP[off] = lo;
        }
    } else {
        if (t < NBUCKET) gcur[t] = 0;
        ushortT* hiP = Wp + (size_t)4*2*16384;
        ushortT* loP = hiP + 2048;
        for (int idx = t; idx < 2048; idx += 256){
            int k = idx >> 4, n = idx & 15;
            ushortT hi, lo;
            split_bf16(We[idx], hi, lo);
            int kc = k >> 5, quad = (k >> 3) & 3, j = k & 7;
            int lane = n + (quad << 4);
            int off = (kc*64 + lane)*8 + j;
            hiP[off] = hi;
            loP[off] = lo;
        }
    }
}

// ---------------- CSR build ----------------
__global__ __launch_bounds__(256) void k_bucketA(const int* __restrict__ ei,
                                                 int* __restrict__ gcur,
                                                 uintT* __restrict__ bucket){
    __shared__ int hist[NBUCKET];
    __shared__ int base[NBUCKET];
    int t = threadIdx.x;
    if (t < NBUCKET) hist[t] = 0;
    __syncthreads();
    int e0 = blockIdx.x * EPWA;
    int cr_c[12], cr_r[12];
    #pragma unroll
    for (int p = 0; p < 12; p++){
        int e = e0 + p*256 + t;
        if (e < NEDGES){
            cr_r[p] = ei[e];
            cr_c[p] = ei[NEDGES + e];
            atomicAdd(&hist[cr_c[p] >> 8], 1);
        } else cr_c[p] = -1;
    }
    __syncthreads();
    if (t < NBUCKET){
        base[t] = atomicAdd(&gcur[t], hist[t]);
        hist[t] = 0;   // reuse as local cursor
    }
    __syncthreads();
    #pragma unroll
    for (int p = 0; p < 12; p++){
        int c = cr_c[p];
        if (c >= 0){
            int b = c >> 8;
            int lp = atomicAdd(&hist[b], 1);
            bucket[(size_t)b*BCAP + base[b] + lp] = ((uintT)c << 16) | (uintT)cr_r[p];
        }
    }
}

__global__ __launch_bounds__(256) void k_bucketB(const int* __restrict__ gcur,
                                                 const uintT* __restrict__ bucket,
                                                 int* __restrict__ offs,
                                                 float* __restrict__ dinv,
                                                 ushortT* __restrict__ csr2){
    __shared__ int sm[256];
    __shared__ int hist[256];
    __shared__ int lcur[256];
    int b = blockIdx.x;
    int t = threadIdx.x;
    int n0 = b << 8;

    int gv = (t < NBUCKET) ? gcur[t] : 0;
    sm[t] = gv;
    __syncthreads();
    for (int off = 1; off < 256; off <<= 1){
        int tv = (t >= off) ? sm[t-off] : 0;
        __syncthreads();
        sm[t] += tv;
        __syncthreads();
    }
    __shared__ int bbase_s;
    if (t == b) bbase_s = sm[t] - gv;
    hist[t] = 0;
    __syncthreads();
    int bbase = bbase_s;
    int count = gcur[b];
    const uintT* src = bucket + (size_t)b*BCAP;

    for (int i = t; i < count; i += 256)
        atomicAdd(&hist[(src[i] >> 16) & 255], 1);
    __syncthreads();

    int v = hist[t];
    sm[t] = v;
    __syncthreads();
    for (int off = 1; off < 256; off <<= 1){
        int tv = (t >= off) ? sm[t-off] : 0;
        __syncthreads();
        sm[t] += tv;
        __syncthreads();
    }
    int excl = bbase + sm[t] - v;
    int node = n0 + t;
    if (node <= NNODES) offs[node] = excl;
    if (node < NNODES) dinv[node] = rsqrtf((float)(v + 1));
    if (b == NBUCKET-1 && t == 255) offs[NNODES] = NEDGES;
    lcur[t] = excl;
    __syncthreads();

    for (int i = t; i < count; i += 256){
        uintT e = src[i];
        int pos = atomicAdd(&lcur[(e >> 16) & 255], 1);
        csr2[pos] = (ushortT)(e & 0xFFFFu);
    }
}

// ---------------- MFMA GEMM (fp32 A, layer 1): [N,128]x[128,128] split-bf16 x3 -------
// Out: Ys row-major bf16, scaled by dinv[row].
__global__ __launch_bounds__(256) void k_mfma_f32(const float* __restrict__ A,
                                                  const ushortT* __restrict__ Wp,
                                                  const float* __restrict__ scale,
                                                  const float* __restrict__ dinv,
                                                  ushortT* __restrict__ Yb){
    __shared__ float As[64*132];
    int t = threadIdx.x;
    int wave = t >> 6, lane = t & 63;
    int r = lane & 15, quad = lane >> 4;
    int row0 = blockIdx.x*64;
    int m0 = row0 + wave*16;
    const ushortT* WpLo = Wp + 16384;

    #pragma unroll
    for (int p = 0; p < 8; p++){
        int idx = p*256 + t;
        int rr = idx >> 5;
        int c4 = idx & 31;
        int gr = row0 + rr;
        float4 v = make_float4(0.f,0.f,0.f,0.f);
        if (gr < NNODES) v = *(const float4*)&A[(size_t)gr*FDIM + c4*4];
        float4 s = *(const float4*)&scale[c4*4];
        v.x*=s.x; v.y*=s.y; v.z*=s.z; v.w*=s.w;
        *(float4*)&As[rr*132 + c4*4] = v;
    }
    __syncthreads();

    floatx4 acc[8];
    #pragma unroll
    for (int nt = 0; nt < 8; nt++) acc[nt] = (floatx4){0.f,0.f,0.f,0.f};

    int arl = wave*16 + r;
    #pragma unroll
    for (int kc = 0; kc < 4; kc++){
        int kb = kc*32 + quad*8;
        float4 a0 = *(const float4*)&As[arl*132 + kb];
        float4 a1 = *(const float4*)&As[arl*132 + kb + 4];
        float av[8] = {a0.x, a0.y, a0.z, a0.w, a1.x, a1.y, a1.z, a1.w};
        short8 ahi, alo;
        #pragma unroll
        for (int e = 0; e < 8; e++){
            ushortT h, l;
            split_bf16(av[e], h, l);
            ahi[e] = (short)h;
            alo[e] = (short)l;
        }
        #pragma unroll
        for (int nt = 0; nt < 8; nt++){
            size_t boff = (size_t)(((kc*8 + nt)*64 + lane))*8;
            short8 bhi = *(const short8*)&Wp[boff];
            short8 blo = *(const short8*)&WpLo[boff];
            acc[nt] = __builtin_amdgcn_mfma_f32_16x16x32_bf16(ahi, bhi, acc[nt], 0, 0, 0);
            acc[nt] = __builtin_amdgcn_mfma_f32_16x16x32_bf16(alo, bhi, acc[nt], 0, 0, 0);
            acc[nt] = __builtin_amdgcn_mfma_f32_16x16x32_bf16(ahi, blo, acc[nt], 0, 0, 0);
        }
    }

    int orow0 = m0 + quad*4;
    float4 dv = *(const float4*)&dinv[orow0];
    float dva[4] = {dv.x, dv.y, dv.z, dv.w};
    #pragma unroll
    for (int nt = 0; nt < 8; nt++){
        int n = nt*16 + r;
        #pragma unroll
        for (int reg = 0; reg < 4; reg++){
            int orow = orow0 + reg;
            if (orow < NNODES)
                Yb[(size_t)orow*FDIM + n] = f2bf(acc[nt][reg] * dva[reg]);
        }
    }
}

// ---------------- MFMA GEMM (bf16 A, layers 2/3): zero-LDS, split-W x2 --------------
// A bf16 row-major; out Ys row-major bf16 * dinv.
__global__ __launch_bounds__(256) void k_mfma_b16(const ushortT* __restrict__ Ab,
                                                  const ushortT* __restrict__ Wp,
                                                  const float* __restrict__ dinv,
                                                  ushortT* __restrict__ Yb){
    int t = threadIdx.x;
    int wave = t >> 6, lane = t & 63;
    int r = lane & 15, quad = lane >> 4;
    int m0 = blockIdx.x*64 + wave*16;
    int arow = m0 + r;
    if (arow >= NNODES) arow = NNODES - 1;
    const ushortT* WpLo = Wp + 16384;

    floatx4 acc[8];
    #pragma unroll
    for (int nt = 0; nt < 8; nt++) acc[nt] = (floatx4){0.f,0.f,0.f,0.f};

    short8 afr[4];
    #pragma unroll
    for (int kc = 0; kc < 4; kc++)
        afr[kc] = *(const short8*)&Ab[(size_t)arow*FDIM + kc*32 + quad*8];

    #pragma unroll
    for (int kc = 0; kc < 4; kc++){
        #pragma unroll
        for (int nt = 0; nt < 8; nt++){
            size_t boff = (size_t)(((kc*8 + nt)*64 + lane))*8;
            short8 bhi = *(const short8*)&Wp[boff];
            short8 blo = *(const short8*)&WpLo[boff];
            acc[nt] = __builtin_amdgcn_mfma_f32_16x16x32_bf16(afr[kc], bhi, acc[nt], 0, 0, 0);
            acc[nt] = __builtin_amdgcn_mfma_f32_16x16x32_bf16(afr[kc], blo, acc[nt], 0, 0, 0);
        }
    }

    int orow0 = m0 + quad*4;
    float4 dv = *(const float4*)&dinv[orow0];
    float dva[4] = {dv.x, dv.y, dv.z, dv.w};
    #pragma unroll
    for (int nt = 0; nt < 8; nt++){
        int n = nt*16 + r;
        #pragma unroll
        for (int reg = 0; reg < 4; reg++){
            int orow = orow0 + reg;
            if (orow < NNODES)
                Yb[(size_t)orow*FDIM + n] = f2bf(acc[nt][reg] * dva[reg]);
        }
    }
}

// ---------------- fused final: out = gelu(H@lw1+lb1)@lw2 + lb2 ----------------------
__global__ __launch_bounds__(256) void k_mfma_final(const ushortT* __restrict__ Ab,
                                                    const ushortT* __restrict__ Wp1,
                                                    const ushortT* __restrict__ Wp2,
                                                    const float* __restrict__ lb1,
                                                    const float* __restrict__ lb2,
                                                    float* __restrict__ out){
    __shared__ ushortT Ls[64*136];
    int t = threadIdx.x;
    int wave = t >> 6, lane = t & 63;
    int r = lane & 15, quad = lane >> 4;
    int row0 = blockIdx.x*64;
    int m0 = row0 + wave*16;
    int arow = m0 + r;
    if (arow >= NNODES) arow = NNODES - 1;
    const ushortT* Wp1Lo = Wp1 + 16384;
    const ushortT* Wp2Lo = Wp2 + 2048;

    floatx4 acc[8];
    #pragma unroll
    for (int nt = 0; nt < 8; nt++) acc[nt] = (floatx4){0.f,0.f,0.f,0.f};

    short8 afr[4];
    #pragma unroll
    for (int kc = 0; kc < 4; kc++)
        afr[kc] = *(const short8*)&Ab[(size_t)arow*FDIM + kc*32 + quad*8];

    #pragma unroll
    for (int kc = 0; kc < 4; kc++){
        #pragma unroll
        for (int nt = 0; nt < 8; nt++){
            size_t boff = (size_t)(((kc*8 + nt)*64 + lane))*8;
            short8 bhi = *(const short8*)&Wp1[boff];
            short8 blo = *(const short8*)&Wp1Lo[boff];
            acc[nt] = __builtin_amdgcn_mfma_f32_16x16x32_bf16(afr[kc], bhi, acc[nt], 0, 0, 0);
            acc[nt] = __builtin_amdgcn_mfma_f32_16x16x32_bf16(afr[kc], blo, acc[nt], 0, 0, 0);
        }
    }

    int lrow0 = wave*16 + quad*4;
    #pragma unroll
    for (int nt = 0; nt < 8; nt++){
        int n = nt*16 + r;
        float bv = lb1[n];
        #pragma unroll
        for (int reg = 0; reg < 4; reg++)
            Ls[(lrow0 + reg)*136 + n] = f2bf(gelu_erf(acc[nt][reg] + bv));
    }
    __syncthreads();

    floatx4 acc2 = (floatx4){0.f,0.f,0.f,0.f};
    #pragma unroll
    for (int kc = 0; kc < 4; kc++){
        short8 a2 = *(const short8*)&Ls[(wave*16 + r)*136 + kc*32 + quad*8];
        short8 bhi = *(const short8*)&Wp2[(size_t)(kc*64 + lane)*8];
        short8 blo = *(const short8*)&Wp2Lo[(size_t)(kc*64 + lane)*8];
        acc2 = __builtin_amdgcn_mfma_f32_16x16x32_bf16(a2, bhi, acc2, 0, 0, 0);
        acc2 = __builtin_amdgcn_mfma_f32_16x16x32_bf16(a2, blo, acc2, 0, 0, 0);
    }
    float bv2 = lb2[r];
    #pragma unroll
    for (int reg = 0; reg < 4; reg++){
        int orow = m0 + quad*4 + reg;
        if (orow < NNODES)
            out[(size_t)orow*16 + r] = acc2[reg] + bv2;
    }
}

// ---------------- full-row aggregation: 32 lanes x uint2 per node -------------------
// Y row-major bf16 (64 uints/node). One pass: gather 256B/node/edge, wave = 2 nodes.
__global__ __launch_bounds__(256) void k_aggregate(const uintT* __restrict__ Y2,
                                                   const float* __restrict__ dinv,
                                                   const int* __restrict__ offs,
                                                   const ushortT* __restrict__ csr2,
                                                   const float* __restrict__ bias,
                                                   ushortT* __restrict__ Hout){
    int node = blockIdx.x*8 + (threadIdx.x >> 5);
    int lane = threadIdx.x & 31;           // uint2 index: feats 4*lane..4*lane+3
    const uint2* Yu = (const uint2*)Y2;    // 32 uint2 per node

    uint2 a0 = Yu[(size_t)node*32 + lane];
    float4 acc;
    acc.x = bflo(a0.x); acc.y = bfhi(a0.x);
    acc.z = bflo(a0.y); acc.w = bfhi(a0.y);
    int e0 = offs[node], e1 = offs[node+1];
    int e = e0;
    for (; e + 7 < e1; e += 8){
        int s0 = csr2[e+0];
        int s1 = csr2[e+1];
        int s2 = csr2[e+2];
        int s3 = csr2[e+3];
        int s4 = csr2[e+4];
        int s5 = csr2[e+5];
        int s6 = csr2[e+6];
        int s7 = csr2[e+7];
        uint2 q0 = Yu[(size_t)s0*32 + lane];
        uint2 q1 = Yu[(size_t)s1*32 + lane];
        uint2 q2 = Yu[(size_t)s2*32 + lane];
        uint2 q3 = Yu[(size_t)s3*32 + lane];
        uint2 q4 = Yu[(size_t)s4*32 + lane];
        uint2 q5 = Yu[(size_t)s5*32 + lane];
        uint2 q6 = Yu[(size_t)s6*32 + lane];
        uint2 q7 = Yu[(size_t)s7*32 + lane];
        acc.x += bflo(q0.x); acc.y += bfhi(q0.x); acc.z += bflo(q0.y); acc.w += bfhi(q0.y);
        acc.x += bflo(q1.x); acc.y += bfhi(q1.x); acc.z += bflo(q1.y); acc.w += bfhi(q1.y);
        acc.x += bflo(q2.x); acc.y += bfhi(q2.x); acc.z += bflo(q2.y); acc.w += bfhi(q2.y);
        acc.x += bflo(q3.x); acc.y += bfhi(q3.x); acc.z += bflo(q3.y); acc.w += bfhi(q3.y);
        acc.x += bflo(q4.x); acc.y += bfhi(q4.x); acc.z += bflo(q4.y); acc.w += bfhi(q4.y);
        acc.x += bflo(q5.x); acc.y += bfhi(q5.x); acc.z += bflo(q5.y); acc.w += bfhi(q5.y);
        acc.x += bflo(q6.x); acc.y += bfhi(q6.x); acc.z += bflo(q6.y); acc.w += bfhi(q6.y);
        acc.x += bflo(q7.x); acc.y += bfhi(q7.x); acc.z += bflo(q7.y); acc.w += bfhi(q7.y);
    }
    for (; e + 1 < e1; e += 2){
        int s0 = csr2[e], s1 = csr2[e+1];
        uint2 q0 = Yu[(size_t)s0*32 + lane];
        uint2 q1 = Yu[(size_t)s1*32 + lane];
        acc.x += bflo(q0.x); acc.y += bfhi(q0.x); acc.z += bflo(q0.y); acc.w += bfhi(q0.y);
        acc.x += bflo(q1.x); acc.y += bfhi(q1.x); acc.z += bflo(q1.y); acc.w += bfhi(q1.y);
    }
    if (e < e1){
        uint2 q = Yu[(size_t)csr2[e]*32 + lane];
        acc.x += bflo(q.x); acc.y += bfhi(q.x); acc.z += bflo(q.y); acc.w += bfhi(q.y);
    }
    float dc = dinv[node];
    float4 bv = ((const float4*)bias)[lane];
    acc.x = gelu_erf(fmaf(dc, acc.x, bv.x));
    acc.y = gelu_erf(fmaf(dc, acc.y, bv.y));
    acc.z = gelu_erf(fmaf(dc, acc.z, bv.z));
    acc.w = gelu_erf(fmaf(dc, acc.w, bv.w));
    uint2 o;
    o.x = (uintT)f2bf(acc.x) | ((uintT)f2bf(acc.y) << 16);
    o.y = (uintT)f2bf(acc.z) | ((uintT)f2bf(acc.w) << 16);
    *(uint2*)&Hout[(size_t)node*FDIM + lane*4] = o;
}

extern "C" void kernel_launch(void* const* d_in, const int* in_sizes, int n_in,
                              void* d_out, int out_size, void* d_ws, size_t ws_size,
                              hipStream_t stream) {
    const float* x    = (const float*)d_in[0];
    const int*   ei   = (const int*)d_in[1];
    const float* imp  = (const float*)d_in[2];
    const float* W1   = (const float*)d_in[3];
    const float* b1   = (const float*)d_in[4];
    const float* W2   = (const float*)d_in[5];
    const float* b2   = (const float*)d_in[6];
    const float* W3   = (const float*)d_in[7];
    const float* b3   = (const float*)d_in[8];
    const float* lw1  = (const float*)d_in[9];
    const float* lb1  = (const float*)d_in[10];
    const float* lw2  = (const float*)d_in[11];
    const float* lb2  = (const float*)d_in[12];
    float* out = (float*)d_out;

    // workspace layout (units of 4 bytes)
    int*   offs   = (int*)d_ws;                          // 50001 (pad to 50048)
    int*   gcur   = (int*)d_ws + 50048;                  // 196 (pad to 50304)
    float* dinv   = (float*)d_ws + 50304;                // 50000 (pad to 100480)
    ushortT* csr2 = (ushortT*)((int*)d_ws + 100480);     // 800000 ushort (1.6 MB)
    uintT* bucket = (uintT*)((int*)d_ws + 500480);       // 196*6144 uint (4.8 MB)
    ushortT* Wp   = (ushortT*)((int*)d_ws + 1704704);    // 4*32768 + 4096 ushort (~270 KB)
    uintT* bufY   = (uintT*)((int*)d_ws + 1772288);      // 50000*64 uints row-major bf16 (12.8 MB)
    ushortT* bufH = (ushortT*)((int*)d_ws + 4972288);    // 50000*128 bf16 row-major (12.8 MB)

    dim3 B(256);
    // ---- weight prepack (+gcur zero) + CSR build ----
    k_packW  <<<5, B, 0, stream>>>(W1, W2, W3, lw1, lw2, Wp, gcur);
    k_bucketA<<<ABLK, B, 0, stream>>>(ei, gcur, bucket);
    k_bucketB<<<NBUCKET, B, 0, stream>>>(gcur, bucket, offs, dinv, csr2);

    // ---- conv layers ----
    k_mfma_f32 <<<MGRID, B, 0, stream>>>(x, Wp + 0*32768, imp, dinv, (ushortT*)bufY);
    k_aggregate<<<NNODES/8, B, 0, stream>>>(bufY, dinv, offs, csr2, b1, bufH);
    k_mfma_b16 <<<MGRID, B, 0, stream>>>(bufH, Wp + 1*32768, dinv, (ushortT*)bufY);
    k_aggregate<<<NNODES/8, B, 0, stream>>>(bufY, dinv, offs, csr2, b2, bufH);
    k_mfma_b16 <<<MGRID, B, 0, stream>>>(bufH, Wp + 2*32768, dinv, (ushortT*)bufY);
    k_aggregate<<<NNODES/8, B, 0, stream>>>(bufY, dinv, offs, csr2, b3, bufH);

    // ---- out = gelu(H@lw1+lb1)@lw2 + lb2 (fused) ----
    k_mfma_final<<<MGRID, B, 0, stream>>>(bufH, Wp + 3*32768, Wp + 4*32768, lb1, lb2, out);
}

// Round 15
// 298.776 us; speedup vs baseline: 1.1416x; 1.0071x over previous
//
#include <hip/hip_runtime.h>
#include <math.h>

#define NNODES 50000
#define NEDGES 800000
#define FDIM 128
#define NBUCKET 196     // buckets of 256 nodes: 196*256 = 50176 >= 50000
#define BCAP 6144       // capacity per bucket (mean 4082, +32 sigma)
#define ABLK 261        // pass-A workgroups
#define EPWA 3072       // edges per pass-A wg (261*3072 >= 800000)
#define MGRID 782       // ceil(50000/64) MFMA-GEMM blocks

typedef unsigned short ushortT;
typedef unsigned int uintT;
typedef __attribute__((ext_vector_type(8))) short short8;
typedef __attribute__((ext_vector_type(4))) float floatx4;

__device__ __forceinline__ float gelu_erf(float x){
    return 0.5f * x * (1.0f + erff(x * 0.70710678118654752f));
}
// bf16 helpers
__device__ __forceinline__ float bflo(uintT u){ return __uint_as_float(u << 16); }
__device__ __forceinline__ float bfhi(uintT u){ return __uint_as_float(u & 0xFFFF0000u); }
__device__ __forceinline__ ushortT f2bf(float f){
    uintT u = __float_as_uint(f);
    return (ushortT)((u + 0x7FFFu + ((u >> 16) & 1u)) >> 16);   // RNE
}
// truncation split: f = hi + lo_resid; both bf16 (trunc). Residual error ~2^-16 rel.
__device__ __forceinline__ void split_bf16(float f, ushortT& hi, ushortT& lo){
    uintT u = __float_as_uint(f);
    hi = (ushortT)(u >> 16);
    float fhi = __uint_as_float(u & 0xFFFF0000u);
    lo = (ushortT)(__float_as_uint(f - fhi) >> 16);
}

// ---------------- weight prepack + gcur zero ----------------
__global__ __launch_bounds__(256) void k_packW(const float* __restrict__ Wa,
                                               const float* __restrict__ Wb,
                                               const float* __restrict__ Wc,
                                               const float* __restrict__ Wd,
                                               const float* __restrict__ We,
                                               ushortT* __restrict__ Wp,
                                               int* __restrict__ gcur){
    int l = blockIdx.x;
    int t = threadIdx.x;
    if (l < 4){
        const float* W = (l==0) ? Wa : (l==1) ? Wb : (l==2) ? Wc : Wd;
        ushortT* hiP = Wp + (size_t)l*2*16384;
        ushortT* loP = hiP + 16384;
        for (int idx = t; idx < 16384; idx += 256){
            int k = idx >> 7, n = idx & 127;
            ushortT hi, lo;
            split_bf16(W[idx], hi, lo);
            int kc = k >> 5, quad = (k >> 3) & 3, j = k & 7;
            int nt = n >> 4, lane = (n & 15) + (quad << 4);
            int off = ((kc*8 + nt)*64 + lane)*8 + j;
            hiP[off] = hi;
            loP[off] = lo;
        }
    } else {
        if (t < NBUCKET) gcur[t] = 0;
        ushortT* hiP = Wp + (size_t)4*2*16384;
        ushortT* loP = hiP + 2048;
        for (int idx = t; idx < 2048; idx += 256){
            int k = idx >> 4, n = idx & 15;
            ushortT hi, lo;
            split_bf16(We[idx], hi, lo);
            int kc = k >> 5, quad = (k >> 3) & 3, j = k & 7;
            int lane = n + (quad << 4);
            int off = (kc*64 + lane)*8 + j;
            hiP[off] = hi;
            loP[off] = lo;
        }
    }
}

// ---------------- CSR build ----------------
__global__ __launch_bounds__(256) void k_bucketA(const int* __restrict__ ei,
                                                 int* __restrict__ gcur,
                                                 uintT* __restrict__ bucket){
    __shared__ int hist[NBUCKET];
    __shared__ int base[NBUCKET];
    int t = threadIdx.x;
    if (t < NBUCKET) hist[t] = 0;
    __syncthreads();
    int e0 = blockIdx.x * EPWA;
    int cr_c[12], cr_r[12];
    #pragma unroll
    for (int p = 0; p < 12; p++){
        int e = e0 + p*256 + t;
        if (e < NEDGES){
            cr_r[p] = ei[e];
            cr_c[p] = ei[NEDGES + e];
            atomicAdd(&hist[cr_c[p] >> 8], 1);
        } else cr_c[p] = -1;
    }
    __syncthreads();
    if (t < NBUCKET){
        base[t] = atomicAdd(&gcur[t], hist[t]);
        hist[t] = 0;   // reuse as local cursor
    }
    __syncthreads();
    #pragma unroll
    for (int p = 0; p < 12; p++){
        int c = cr_c[p];
        if (c >= 0){
            int b = c >> 8;
            int lp = atomicAdd(&hist[b], 1);
            bucket[(size_t)b*BCAP + base[b] + lp] = ((uintT)c << 16) | (uintT)cr_r[p];
        }
    }
}

__global__ __launch_bounds__(256) void k_bucketB(const int* __restrict__ gcur,
                                                 const uintT* __restrict__ bucket,
                                                 int* __restrict__ offs,
                                                 float* __restrict__ dinv,
                                                 ushortT* __restrict__ csr2){
    __shared__ int sm[256];
    __shared__ int hist[256];
    __shared__ int lcur[256];
    int b = blockIdx.x;
    int t = threadIdx.x;
    int n0 = b << 8;

    int gv = (t < NBUCKET) ? gcur[t] : 0;
    sm[t] = gv;
    __syncthreads();
    for (int off = 1; off < 256; off <<= 1){
        int tv = (t >= off) ? sm[t-off] : 0;
        __syncthreads();
        sm[t] += tv;
        __syncthreads();
    }
    __shared__ int bbase_s;
    if (t == b) bbase_s = sm[t] - gv;
    hist[t] = 0;
    __syncthreads();
    int bbase = bbase_s;
    int count = gcur[b];
    const uintT* src = bucket + (size_t)b*BCAP;

    for (int i = t; i < count; i += 256)
        atomicAdd(&hist[(src[i] >> 16) & 255], 1);
    __syncthreads();

    int v = hist[t];
    sm[t] = v;
    __syncthreads();
    for (int off = 1; off < 256; off <<= 1){
        int tv = (t >= off) ? sm[t-off] : 0;
        __syncthreads();
        sm[t] += tv;
        __syncthreads();
    }
    int excl = bbase + sm[t] - v;
    int node = n0 + t;
    if (node <= NNODES) offs[node] = excl;
    if (node < NNODES) dinv[node] = rsqrtf((float)(v + 1));
    if (b == NBUCKET-1 && t == 255) offs[NNODES] = NEDGES;
    lcur[t] = excl;
    __syncthreads();

    for (int i = t; i < count; i += 256){
        uintT e = src[i];
        int pos = atomicAdd(&lcur[(e >> 16) & 255], 1);
        csr2[pos] = (ushortT)(e & 0xFFFFu);
    }
}

// ---------------- MFMA GEMM (fp32 A, layer 1): [N,128]x[128,128] split-bf16 x3 -------
// Out: Ys row-major bf16, scaled by dinv[row].
__global__ __launch_bounds__(256) void k_mfma_f32(const float* __restrict__ A,
                                                  const ushortT* __restrict__ Wp,
                                                  const float* __restrict__ scale,
                                                  const float* __restrict__ dinv,
                                                  ushortT* __restrict__ Yb){
    __shared__ float As[64*132];
    int t = threadIdx.x;
    int wave = t >> 6, lane = t & 63;
    int r = lane & 15, quad = lane >> 4;
    int row0 = blockIdx.x*64;
    int m0 = row0 + wave*16;
    const ushortT* WpLo = Wp + 16384;

    #pragma unroll
    for (int p = 0; p < 8; p++){
        int idx = p*256 + t;
        int rr = idx >> 5;
        int c4 = idx & 31;
        int gr = row0 + rr;
        float4 v = make_float4(0.f,0.f,0.f,0.f);
        if (gr < NNODES) v = *(const float4*)&A[(size_t)gr*FDIM + c4*4];
        float4 s = *(const float4*)&scale[c4*4];
        v.x*=s.x; v.y*=s.y; v.z*=s.z; v.w*=s.w;
        *(float4*)&As[rr*132 + c4*4] = v;
    }
    __syncthreads();

    floatx4 acc[8];
    #pragma unroll
    for (int nt = 0; nt < 8; nt++) acc[nt] = (floatx4){0.f,0.f,0.f,0.f};

    int arl = wave*16 + r;
    #pragma unroll
    for (int kc = 0; kc < 4; kc++){
        int kb = kc*32 + quad*8;
        float4 a0 = *(const float4*)&As[arl*132 + kb];
        float4 a1 = *(const float4*)&As[arl*132 + kb + 4];
        float av[8] = {a0.x, a0.y, a0.z, a0.w, a1.x, a1.y, a1.z, a1.w};
        short8 ahi, alo;
        #pragma unroll
        for (int e = 0; e < 8; e++){
            ushortT h, l;
            split_bf16(av[e], h, l);
            ahi[e] = (short)h;
            alo[e] = (short)l;
        }
        #pragma unroll
        for (int nt = 0; nt < 8; nt++){
            size_t boff = (size_t)(((kc*8 + nt)*64 + lane))*8;
            short8 bhi = *(const short8*)&Wp[boff];
            short8 blo = *(const short8*)&WpLo[boff];
            acc[nt] = __builtin_amdgcn_mfma_f32_16x16x32_bf16(ahi, bhi, acc[nt], 0, 0, 0);
            acc[nt] = __builtin_amdgcn_mfma_f32_16x16x32_bf16(alo, bhi, acc[nt], 0, 0, 0);
            acc[nt] = __builtin_amdgcn_mfma_f32_16x16x32_bf16(ahi, blo, acc[nt], 0, 0, 0);
        }
    }

    int orow0 = m0 + quad*4;
    float4 dv = *(const float4*)&dinv[orow0];
    float dva[4] = {dv.x, dv.y, dv.z, dv.w};
    #pragma unroll
    for (int nt = 0; nt < 8; nt++){
        int n = nt*16 + r;
        #pragma unroll
        for (int reg = 0; reg < 4; reg++){
            int orow = orow0 + reg;
            if (orow < NNODES)
                Yb[(size_t)orow*FDIM + n] = f2bf(acc[nt][reg] * dva[reg]);
        }
    }
}

// ---------------- MFMA GEMM (bf16 A, layers 2/3): zero-LDS, split-W x2 --------------
__global__ __launch_bounds__(256) void k_mfma_b16(const ushortT* __restrict__ Ab,
                                                  const ushortT* __restrict__ Wp,
                                                  const float* __restrict__ dinv,
                                                  ushortT* __restrict__ Yb){
    int t = threadIdx.x;
    int wave = t >> 6, lane = t & 63;
    int r = lane & 15, quad = lane >> 4;
    int m0 = blockIdx.x*64 + wave*16;
    int arow = m0 + r;
    if (arow >= NNODES) arow = NNODES - 1;
    const ushortT* WpLo = Wp + 16384;

    floatx4 acc[8];
    #pragma unroll
    for (int nt = 0; nt < 8; nt++) acc[nt] = (floatx4){0.f,0.f,0.f,0.f};

    short8 afr[4];
    #pragma unroll
    for (int kc = 0; kc < 4; kc++)
        afr[kc] = *(const short8*)&Ab[(size_t)arow*FDIM + kc*32 + quad*8];

    #pragma unroll
    for (int kc = 0; kc < 4; kc++){
        #pragma unroll
        for (int nt = 0; nt < 8; nt++){
            size_t boff = (size_t)(((kc*8 + nt)*64 + lane))*8;
            short8 bhi = *(const short8*)&Wp[boff];
            short8 blo = *(const short8*)&WpLo[boff];
            acc[nt] = __builtin_amdgcn_mfma_f32_16x16x32_bf16(afr[kc], bhi, acc[nt], 0, 0, 0);
            acc[nt] = __builtin_amdgcn_mfma_f32_16x16x32_bf16(afr[kc], blo, acc[nt], 0, 0, 0);
        }
    }

    int orow0 = m0 + quad*4;
    float4 dv = *(const float4*)&dinv[orow0];
    float dva[4] = {dv.x, dv.y, dv.z, dv.w};
    #pragma unroll
    for (int nt = 0; nt < 8; nt++){
        int n = nt*16 + r;
        #pragma unroll
        for (int reg = 0; reg < 4; reg++){
            int orow = orow0 + reg;
            if (orow < NNODES)
                Yb[(size_t)orow*FDIM + n] = f2bf(acc[nt][reg] * dva[reg]);
        }
    }
}

// ---------------- fused final: out = gelu(H@lw1+lb1)@lw2 + lb2 ----------------------
__global__ __launch_bounds__(256) void k_mfma_final(const ushortT* __restrict__ Ab,
                                                    const ushortT* __restrict__ Wp1,
                                                    const ushortT* __restrict__ Wp2,
                                                    const float* __restrict__ lb1,
                                                    const float* __restrict__ lb2,
                                                    float* __restrict__ out){
    __shared__ ushortT Ls[64*136];
    int t = threadIdx.x;
    int wave = t >> 6, lane = t & 63;
    int r = lane & 15, quad = lane >> 4;
    int row0 = blockIdx.x*64;
    int m0 = row0 + wave*16;
    int arow = m0 + r;
    if (arow >= NNODES) arow = NNODES - 1;
    const ushortT* Wp1Lo = Wp1 + 16384;
    const ushortT* Wp2Lo = Wp2 + 2048;

    floatx4 acc[8];
    #pragma unroll
    for (int nt = 0; nt < 8; nt++) acc[nt] = (floatx4){0.f,0.f,0.f,0.f};

    short8 afr[4];
    #pragma unroll
    for (int kc = 0; kc < 4; kc++)
        afr[kc] = *(const short8*)&Ab[(size_t)arow*FDIM + kc*32 + quad*8];

    #pragma unroll
    for (int kc = 0; kc < 4; kc++){
        #pragma unroll
        for (int nt = 0; nt < 8; nt++){
            size_t boff = (size_t)(((kc*8 + nt)*64 + lane))*8;
            short8 bhi = *(const short8*)&Wp1[boff];
            short8 blo = *(const short8*)&Wp1Lo[boff];
            acc[nt] = __builtin_amdgcn_mfma_f32_16x16x32_bf16(afr[kc], bhi, acc[nt], 0, 0, 0);
            acc[nt] = __builtin_amdgcn_mfma_f32_16x16x32_bf16(afr[kc], blo, acc[nt], 0, 0, 0);
        }
    }

    int lrow0 = wave*16 + quad*4;
    #pragma unroll
    for (int nt = 0; nt < 8; nt++){
        int n = nt*16 + r;
        float bv = lb1[n];
        #pragma unroll
        for (int reg = 0; reg < 4; reg++)
            Ls[(lrow0 + reg)*136 + n] = f2bf(gelu_erf(acc[nt][reg] + bv));
    }
    __syncthreads();

    floatx4 acc2 = (floatx4){0.f,0.f,0.f,0.f};
    #pragma unroll
    for (int kc = 0; kc < 4; kc++){
        short8 a2 = *(const short8*)&Ls[(wave*16 + r)*136 + kc*32 + quad*8];
        short8 bhi = *(const short8*)&Wp2[(size_t)(kc*64 + lane)*8];
        short8 blo = *(const short8*)&Wp2Lo[(size_t)(kc*64 + lane)*8];
        acc2 = __builtin_amdgcn_mfma_f32_16x16x32_bf16(a2, bhi, acc2, 0, 0, 0);
        acc2 = __builtin_amdgcn_mfma_f32_16x16x32_bf16(a2, blo, acc2, 0, 0, 0);
    }
    float bv2 = lb2[r];
    #pragma unroll
    for (int reg = 0; reg < 4; reg++){
        int orow = m0 + quad*4 + reg;
        if (orow < NNODES)
            out[(size_t)orow*16 + r] = acc2[reg] + bv2;
    }
}

// ---------------- full-row aggregation: 16 lanes x uint4 per node -------------------
// Y row-major bf16 (64 uints/node). Wave = 4 nodes; one VMEM instr serves 4 edges.
__global__ __launch_bounds__(256) void k_aggregate(const uintT* __restrict__ Y2,
                                                   const float* __restrict__ dinv,
                                                   const int* __restrict__ offs,
                                                   const ushortT* __restrict__ csr2,
                                                   const float* __restrict__ bias,
                                                   ushortT* __restrict__ Hout){
    int node = blockIdx.x*16 + (threadIdx.x >> 4);
    int lane = threadIdx.x & 15;           // uint4 index: feats 8*lane..8*lane+7
    const uint4* Yu = (const uint4*)Y2;    // 16 uint4 per node

    uint4 a0 = Yu[(size_t)node*16 + lane];
    float4 accA, accB;
    accA.x = bflo(a0.x); accA.y = bfhi(a0.x);
    accA.z = bflo(a0.y); accA.w = bfhi(a0.y);
    accB.x = bflo(a0.z); accB.y = bfhi(a0.z);
    accB.z = bflo(a0.w); accB.w = bfhi(a0.w);
    int e0 = offs[node], e1 = offs[node+1];
    int e = e0;
    for (; e + 7 < e1; e += 8){
        int s0 = csr2[e+0];
        int s1 = csr2[e+1];
        int s2 = csr2[e+2];
        int s3 = csr2[e+3];
        int s4 = csr2[e+4];
        int s5 = csr2[e+5];
        int s6 = csr2[e+6];
        int s7 = csr2[e+7];
        uint4 q0 = Yu[(size_t)s0*16 + lane];
        uint4 q1 = Yu[(size_t)s1*16 + lane];
        uint4 q2 = Yu[(size_t)s2*16 + lane];
        uint4 q3 = Yu[(size_t)s3*16 + lane];
        uint4 q4 = Yu[(size_t)s4*16 + lane];
        uint4 q5 = Yu[(size_t)s5*16 + lane];
        uint4 q6 = Yu[(size_t)s6*16 + lane];
        uint4 q7 = Yu[(size_t)s7*16 + lane];
        accA.x += bflo(q0.x); accA.y += bfhi(q0.x); accA.z += bflo(q0.y); accA.w += bfhi(q0.y);
        accB.x += bflo(q0.z); accB.y += bfhi(q0.z); accB.z += bflo(q0.w); accB.w += bfhi(q0.w);
        accA.x += bflo(q1.x); accA.y += bfhi(q1.x); accA.z += bflo(q1.y); accA.w += bfhi(q1.y);
        accB.x += bflo(q1.z); accB.y += bfhi(q1.z); accB.z += bflo(q1.w); accB.w += bfhi(q1.w);
        accA.x += bflo(q2.x); accA.y += bfhi(q2.x); accA.z += bflo(q2.y); accA.w += bfhi(q2.y);
        accB.x += bflo(q2.z); accB.y += bfhi(q2.z); accB.z += bflo(q2.w); accB.w += bfhi(q2.w);
        accA.x += bflo(q3.x); accA.y += bfhi(q3.x); accA.z += bflo(q3.y); accA.w += bfhi(q3.y);
        accB.x += bflo(q3.z); accB.y += bfhi(q3.z); accB.z += bflo(q3.w); accB.w += bfhi(q3.w);
        accA.x += bflo(q4.x); accA.y += bfhi(q4.x); accA.z += bflo(q4.y); accA.w += bfhi(q4.y);
        accB.x += bflo(q4.z); accB.y += bfhi(q4.z); accB.z += bflo(q4.w); accB.w += bfhi(q4.w);
        accA.x += bflo(q5.x); accA.y += bfhi(q5.x); accA.z += bflo(q5.y); accA.w += bfhi(q5.y);
        accB.x += bflo(q5.z); accB.y += bfhi(q5.z); accB.z += bflo(q5.w); accB.w += bfhi(q5.w);
        accA.x += bflo(q6.x); accA.y += bfhi(q6.x); accA.z += bflo(q6.y); accA.w += bfhi(q6.y);
        accB.x += bflo(q6.z); accB.y += bfhi(q6.z); accB.z += bflo(q6.w); accB.w += bfhi(q6.w);
        accA.x += bflo(q7.x); accA.y += bfhi(q7.x); accA.z += bflo(q7.y); accA.w += bfhi(q7.y);
        accB.x += bflo(q7.z); accB.y += bfhi(q7.z); accB.z += bflo(q7.w); accB.w += bfhi(q7.w);
    }
    for (; e + 1 < e1; e += 2){
        int s0 = csr2[e], s1 = csr2[e+1];
        uint4 q0 = Yu[(size_t)s0*16 + lane];
        uint4 q1 = Yu[(size_t)s1*16 + lane];
        accA.x += bflo(q0.x); accA.y += bfhi(q0.x); accA.z += bflo(q0.y); accA.w += bfhi(q0.y);
        accB.x += bflo(q0.z); accB.y += bfhi(q0.z); accB.z += bflo(q0.w); accB.w += bfhi(q0.w);
        accA.x += bflo(q1.x); accA.y += bfhi(q1.x); accA.z += bflo(q1.y); accA.w += bfhi(q1.y);
        accB.x += bflo(q1.z); accB.y += bfhi(q1.z); accB.z += bflo(q1.w); accB.w += bfhi(q1.w);
    }
    if (e < e1){
        uint4 q = Yu[(size_t)csr2[e]*16 + lane];
        accA.x += bflo(q.x); accA.y += bfhi(q.x); accA.z += bflo(q.y); accA.w += bfhi(q.y);
        accB.x += bflo(q.z); accB.y += bfhi(q.z); accB.z += bflo(q.w); accB.w += bfhi(q.w);
    }
    float dc = dinv[node];
    float4 bv0 = ((const float4*)bias)[lane*2];
    float4 bv1 = ((const float4*)bias)[lane*2 + 1];
    accA.x = gelu_erf(fmaf(dc, accA.x, bv0.x));
    accA.y = gelu_erf(fmaf(dc, accA.y, bv0.y));
    accA.z = gelu_erf(fmaf(dc, accA.z, bv0.z));
    accA.w = gelu_erf(fmaf(dc, accA.w, bv0.w));
    accB.x = gelu_erf(fmaf(dc, accB.x, bv1.x));
    accB.y = gelu_erf(fmaf(dc, accB.y, bv1.y));
    accB.z = gelu_erf(fmaf(dc, accB.z, bv1.z));
    accB.w = gelu_erf(fmaf(dc, accB.w, bv1.w));
    uint4 o;
    o.x = (uintT)f2bf(accA.x) | ((uintT)f2bf(accA.y) << 16);
    o.y = (uintT)f2bf(accA.z) | ((uintT)f2bf(accA.w) << 16);
    o.z = (uintT)f2bf(accB.x) | ((uintT)f2bf(accB.y) << 16);
    o.w = (uintT)f2bf(accB.z) | ((uintT)f2bf(accB.w) << 16);
    *(uint4*)&Hout[(size_t)node*FDIM + lane*8] = o;
}

extern "C" void kernel_launch(void* const* d_in, const int* in_sizes, int n_in,
                              void* d_out, int out_size, void* d_ws, size_t ws_size,
                              hipStream_t stream) {
    const float* x    = (const float*)d_in[0];
    const int*   ei   = (const int*)d_in[1];
    const float* imp  = (const float*)d_in[2];
    const float* W1   = (const float*)d_in[3];
    const float* b1   = (const float*)d_in[4];
    const float* W2   = (const float*)d_in[5];
    const float* b2   = (const float*)d_in[6];
    const float* W3   = (const float*)d_in[7];
    const float* b3   = (const float*)d_in[8];
    const float* lw1  = (const float*)d_in[9];
    const float* lb1  = (const float*)d_in[10];
    const float* lw2  = (const float*)d_in[11];
    const float* lb2  = (const float*)d_in[12];
    float* out = (float*)d_out;

    // workspace layout (units of 4 bytes)
    int*   offs   = (int*)d_ws;                          // 50001 (pad to 50048)
    int*   gcur   = (int*)d_ws + 50048;                  // 196 (pad to 50304)
    float* dinv   = (float*)d_ws + 50304;                // 50000 (pad to 100480)
    ushortT* csr2 = (ushortT*)((int*)d_ws + 100480);     // 800000 ushort (1.6 MB)
    uintT* bucket = (uintT*)((int*)d_ws + 500480);       // 196*6144 uint (4.8 MB)
    ushortT* Wp   = (ushortT*)((int*)d_ws + 1704704);    // 4*32768 + 4096 ushort (~270 KB)
    uintT* bufY   = (uintT*)((int*)d_ws + 1772288);      // 50000*64 uints row-major bf16 (12.8 MB)
    ushortT* bufH = (ushortT*)((int*)d_ws + 4972288);    // 50000*128 bf16 row-major (12.8 MB)

    dim3 B(256);
    // ---- weight prepack (+gcur zero) + CSR build ----
    k_packW  <<<5, B, 0, stream>>>(W1, W2, W3, lw1, lw2, Wp, gcur);
    k_bucketA<<<ABLK, B, 0, stream>>>(ei, gcur, bucket);
    k_bucketB<<<NBUCKET, B, 0, stream>>>(gcur, bucket, offs, dinv, csr2);

    // ---- conv layers ----
    k_mfma_f32 <<<MGRID, B, 0, stream>>>(x, Wp + 0*32768, imp, dinv, (ushortT*)bufY);
    k_aggregate<<<NNODES/16, B, 0, stream>>>(bufY, dinv, offs, csr2, b1, bufH);
    k_mfma_b16 <<<MGRID, B, 0, stream>>>(bufH, Wp + 1*32768, dinv, (ushortT*)bufY);
    k_aggregate<<<NNODES/16, B, 0, stream>>>(bufY, dinv, offs, csr2, b2, bufH);
    k_mfma_b16 <<<MGRID, B, 0, stream>>>(bufH, Wp + 2*32768, dinv, (ushortT*)bufY);
    k_aggregate<<<NNODES/16, B, 0, stream>>>(bufY, dinv, offs, csr2, b3, bufH);

    // ---- out = gelu(H@lw1+lb1)@lw2 + lb2 (fused) ----
    k_mfma_final<<<MGRID, B, 0, stream>>>(bufH, Wp + 3*32768, Wp + 4*32768, lb1, lb2, out);
}